// Round 10
// baseline (177.789 us; speedup 1.0000x reference)
//
#include <hip/hip_runtime.h>

#define NPTS 2048
#define TPB  768    // 12 waves/block; 2 cells/thread; capacity 1536
#define CAP  1536   // own 1024 + 512 ghost wedge (>= 499 steps of cone)

typedef float v2f __attribute__((ext_vector_type(2)));

// Barrier WITHOUT the vmcnt(0) drain __syncthreads() would emit:
// LDS writes must be visible (lgkmcnt), global stores may stay in flight.
#define EDGE_BARRIER() do {                                   \
    asm volatile("s_waitcnt lgkmcnt(0)" ::: "memory");        \
    __builtin_amdgcn_s_barrier();                             \
    asm volatile("" ::: "memory");                            \
} while (0)

__device__ __forceinline__ v2f s2(float x) { v2f v; v.x = x; v.y = x; return v; }

// packed fma: lowers to v_pk_fma_f32 (2 f32 FMA / lane / instr)
__device__ __forceinline__ v2f fma2(v2f a, v2f b, v2f c) {
#if __has_builtin(__builtin_elementwise_fma)
    return __builtin_elementwise_fma(a, b, c);
#else
    v2f r; r.x = fmaf(a.x, b.x, c.x); r.y = fmaf(a.y, b.y, c.y); return r;
#endif
}

// g = 0.5*f(u) = u*(0.75 + u*(9.375 + u*(-25.25 + u*(18.75 - 3.125 u^2))))
// p = f'(u)    = 1.5 + u*(37.5 + u*(-151.5 + u*(150 - 37.5 u^2)))
__device__ __forceinline__ void eval_gp2(v2f u, v2f& g, v2f& p) {
    const v2f uu = u * u;
    v2f gg = fma2(uu, s2(-3.125f), s2(18.75f));
    gg = fma2(u, gg, s2(-25.25f));
    gg = fma2(u, gg, s2(9.375f));
    gg = fma2(u, gg, s2(0.75f));
    g = u * gg;
    v2f pp = fma2(uu, s2(-37.5f), s2(150.0f));
    pp = fma2(u, pp, s2(-151.5f));
    pp = fma2(u, pp, s2(37.5f));
    p = fma2(u, pp, s2(1.5f));
}

// Grid = 2 blocks per row (256 blocks -> all 256 CUs). Block (r,h) evolves
// 1536 cells autonomously: own 1024 + 512-wide ghost wedge toward the
// partner; clamp junk advances 1 cell/step so own cells are exact through
// t=499. LDS carries ONLY u, split into even/odd arrays so all halo
// accesses are stride-1 (conflict-free); halo g,p recomputed locally
// (packed) — trades idle VALU for the saturated LDS pipe.
__global__ __launch_bounds__(TPB) void lxf_split(
    const float* __restrict__ init, float* __restrict__ out,
    int nbatch, int nsteps)
{
    __shared__ float UL[2][TPB];   // UL[b][i] = u[2i]   (first of pair)
    __shared__ float UR[2][TPB];   // UR[b][i] = u[2i+1] (last of pair)

    const int blk = blockIdx.x;
    const int r   = blk >> 1;            // row
    const int h   = blk & 1;             // 0 -> global [0,1536), 1 -> [512,2048)
    const int tid = threadIdx.x;
    const int c0  = 2 * tid;             // local first cell
    const int gb  = h ? 512 : 0;         // local -> global offset
    const size_t rowoff = (size_t)r * NPTS;
    const float lam = 0.1024f;           // DT/DX (exact in f32)

    const bool st  = h ? (c0 >= 512) : (c0 < 1024);      // own-cell store mask
    const bool bcL = (h == 0) && (tid == 0);             // global cell 0
    const bool bcR = (h == 1) && (tid == TPB - 1);       // global cell 2047
    const int  tl  = (tid == 0)       ? 0   : tid - 1;   // pair index of u[c0-1]
    const int  tr  = (tid == TPB - 1) ? tid : tid + 1;   // pair index of u[c0+2]
    // cone distance into the wedge (margin 2); active while dist <= rem
    const int dist = h ? (509 - c0) : (c0 - 1025);

    // ---- load init cells, eval g/p, write t=0, publish buf 0 ----
    v2f uv = *reinterpret_cast<const v2f*>(init + rowoff + gb + c0);
    v2f gv, pv;
    eval_gp2(uv, gv, pv);

    if (st) *reinterpret_cast<v2f*>(out + rowoff + gb + c0) = uv;

    UL[0][tid] = uv.x;
    UR[0][tid] = uv.y;
    EDGE_BARRIER();

    const size_t stride = (size_t)nbatch * NPTS;    // floats per step
    float* dstw = out + rowoff + gb + c0;

#define STEP(CUR, NXT) do {                                              \
    dstw += stride;                                                      \
    if (dist <= rem) {                                                   \
        v2f h2; h2.x = UR[CUR][tl]; h2.y = UL[CUR][tr];  /* uL, uR */    \
        v2f gh, ph;                                                      \
        eval_gp2(h2, gh, ph);                                            \
        const float aL = fmaxf(fabsf(ph.x), fabsf(pv.x));                \
        const float aM = fmaxf(fabsf(pv.x), fabsf(pv.y));                \
        const float aR = fmaxf(fabsf(pv.y), fabsf(ph.y));                \
        const float fhL = fmaf(-0.5f * aL, uv.x - h2.x, gh.x + gv.x);    \
        const float fhM = fmaf(-0.5f * aM, uv.y - uv.x, gv.x + gv.y);    \
        const float fhR = fmaf(-0.5f * aR, h2.y - uv.y, gv.y + gh.y);    \
        float n0 = fmaf(-lam, fhM - fhL, uv.x);                          \
        float n1 = fmaf(-lam, fhR - fhM, uv.y);                          \
        if (bcL) n0 = n1;   /* u[0]   = u[1]   */                        \
        if (bcR) n1 = n0;   /* u[N-1] = u[N-2] */                        \
        uv.x = n0; uv.y = n1;                                            \
        eval_gp2(uv, gv, pv);                                            \
        UL[NXT][tid] = n0;                                               \
        UR[NXT][tid] = n1;                                               \
        if (st) *reinterpret_cast<v2f*>(dstw) = uv;                      \
    }                                                                    \
    --rem;                                                               \
    EDGE_BARRIER();                                                      \
} while (0)

    const int S  = nsteps - 1;   // 499
    int rem = S - 1;             // remaining steps AFTER the current one
    const int P2 = S >> 1;       // 249
    for (int i = 0; i < P2; ++i) {
        STEP(0, 1);
        STEP(1, 0);
    }
    if (S & 1) STEP(0, 1);
#undef STEP
}

extern "C" void kernel_launch(void* const* d_in, const int* in_sizes, int n_in,
                              void* d_out, int out_size, void* d_ws, size_t ws_size,
                              hipStream_t stream) {
    const float* init = (const float*)d_in[0];
    float* out = (float*)d_out;

    const int nbatch = in_sizes[0] / NPTS;       // 128
    const int nsteps = out_size / in_sizes[0];   // 500

    hipLaunchKernelGGL(lxf_split, dim3(2 * nbatch), dim3(TPB), 0, stream,
                       init, out, nbatch, nsteps);
}